// Round 1
// baseline (169.372 us; speedup 1.0000x reference)
//
#include <hip/hip_runtime.h>

// MipRayMarcher2: NeuS-style alpha compositing along rays.
// One wave (64 lanes) per ray; lane i handles sample i (S=48), interval i (SM=47).

static constexpr int B_ = 4;
static constexpr int R_ = 16384;
static constexpr int NRAYS = B_ * R_;               // 65536
static constexpr int S_ = 48;
static constexpr int SM = S_ - 1;                   // 47
static constexpr int OFF_DEPTH  = NRAYS * 3;        // 196608
static constexpr int OFF_W      = OFF_DEPTH + NRAYS;        // 262144
static constexpr int OFF_NORMAL = OFF_W + NRAYS * SM;       // 3342336

__device__ __forceinline__ float wave_sum64(float x) {
#pragma unroll
    for (int off = 32; off > 0; off >>= 1)
        x += __shfl_xor(x, off, 64);
    return x;
}

__global__ __launch_bounds__(256) void march_kernel(
    const float* __restrict__ colors,
    const float* __restrict__ sdfs,
    const float* __restrict__ depths,
    const float* __restrict__ normals,
    const float* __restrict__ ray_dirs,
    const float* __restrict__ real_normals,
    const float* __restrict__ inv_std_p,
    float* __restrict__ out)
{
    const int wave = threadIdx.x >> 6;
    const int lane = threadIdx.x & 63;
    const int ray  = (blockIdx.x << 2) + wave;   // grid is exact: 16384*4 == NRAYS

    // inv_std = clip(exp(10*p), 1e-6, 1e6)   (wave-uniform)
    const float inv_std = fminf(fmaxf(expf(inv_std_p[0] * 10.0f), 1e-6f), 1e6f);

    // Ray direction (wave-uniform address -> scalarized/broadcast load)
    const float d0 = ray_dirs[(size_t)ray * 3 + 0];
    const float d1 = ray_dirs[(size_t)ray * 3 + 1];
    const float d2 = ray_dirs[(size_t)ray * 3 + 2];

    // Per-sample loads: lane i -> sample i. Contiguous across lanes.
    float c0 = 0.f, c1 = 0.f, c2 = 0.f;
    float sd = 0.f, dp = 0.f;
    float n0 = 0.f, n1 = 0.f, n2 = 0.f;
    float rn0 = 0.f, rn1 = 0.f, rn2 = 0.f;
    if (lane < S_) {
        const size_t b3 = (size_t)ray * S_ * 3 + (size_t)lane * 3;
        const size_t b1 = (size_t)ray * S_ + lane;
        c0 = colors[b3 + 0];  c1 = colors[b3 + 1];  c2 = colors[b3 + 2];
        sd = sdfs[b1];
        dp = depths[b1];
        n0 = normals[b3 + 0]; n1 = normals[b3 + 1]; n2 = normals[b3 + 2];
        rn0 = real_normals[b3 + 0]; rn1 = real_normals[b3 + 1]; rn2 = real_normals[b3 + 2];
    }

    // Neighbor (sample i+1) via shuffle.
    const float c0n = __shfl_down(c0, 1, 64);
    const float c1n = __shfl_down(c1, 1, 64);
    const float c2n = __shfl_down(c2, 1, 64);
    const float sdn = __shfl_down(sd, 1, 64);
    const float dpn = __shfl_down(dp, 1, 64);
    const float n0n = __shfl_down(n0, 1, 64);
    const float n1n = __shfl_down(n1, 1, 64);
    const float n2n = __shfl_down(n2, 1, 64);
    const float rn0n = __shfl_down(rn0, 1, 64);
    const float rn1n = __shfl_down(rn1, 1, 64);
    const float rn2n = __shfl_down(rn2, 1, 64);

    float alpha = 0.f;
    float t = 1.f;
    float cm0 = 0.f, cm1 = 0.f, cm2 = 0.f, dpm = 0.f;
    float rm0 = 0.f, rm1 = 0.f, rm2 = 0.f;
    if (lane < SM) {
        const float delta = dpn - dp;
        cm0 = (c0 + c0n) * 0.5f;
        cm1 = (c1 + c1n) * 0.5f;
        cm2 = (c2 + c2n) * 0.5f;
        const float sdm = (sd + sdn) * 0.5f;
        dpm = (dp + dpn) * 0.5f;
        const float nm0 = (n0 + n0n) * 0.5f;
        const float nm1 = (n1 + n1n) * 0.5f;
        const float nm2 = (n2 + n2n) * 0.5f;
        rm0 = (rn0 + rn0n) * 0.5f;
        rm1 = (rn1 + rn1n) * 0.5f;
        rm2 = (rn2 + rn2n) * 0.5f;

        const float true_cos = d0 * nm0 + d1 * nm1 + d2 * nm2;
        const float iter_cos = fminf(true_cos, 0.0f);        // -relu(-x)
        const float h = iter_cos * delta * 0.5f;
        const float est_next = sdm + h;
        const float est_prev = sdm - h;
        const float prev_cdf = 1.0f / (1.0f + expf(-est_prev * inv_std));
        const float next_cdf = 1.0f / (1.0f + expf(-est_next * inv_std));
        alpha = (prev_cdf - next_cdf + 1e-5f) / (prev_cdf + 1e-5f);
        alpha = fminf(fmaxf(alpha, 0.0f), 1.0f);
        t = 1.0f - alpha + 1e-10f;
    }

    // Exclusive prefix product of t across lanes -> transmittance.
    float p = t;
#pragma unroll
    for (int off = 1; off < 64; off <<= 1) {
        const float v = __shfl_up(p, off, 64);
        if (lane >= off) p *= v;
    }
    float trans = __shfl_up(p, 1, 64);
    if (lane == 0) trans = 1.0f;

    const float w = alpha * trans;   // 0 for lanes >= SM

    // Reductions.
    const float ws   = wave_sum64(w);
    const float swc0 = wave_sum64(w * cm0);
    const float swc1 = wave_sum64(w * cm1);
    const float swc2 = wave_sum64(w * cm2);
    const float swd  = wave_sum64(w * dpm);
    const float swn0 = wave_sum64(w * rm0);
    const float swn1 = wave_sum64(w * rm1);
    const float swn2 = wave_sum64(w * rm2);

    // Outputs.
    if (lane < SM)
        out[OFF_W + (size_t)ray * SM + lane] = w;

    if (lane == 0) {
        out[(size_t)ray * 3 + 0] = swc0;
        out[(size_t)ray * 3 + 1] = swc1;
        out[(size_t)ray * 3 + 2] = swc2;
        const float inv_ws = 1.0f / ws;   // ws >= ~1e-5 guaranteed (alpha >= 1e-5/(1+1e-5))
        out[OFF_DEPTH + ray] = swd * inv_ws;
        out[OFF_NORMAL + (size_t)ray * 3 + 0] = swn0 * inv_ws;
        out[OFF_NORMAL + (size_t)ray * 3 + 1] = swn1 * inv_ws;
        out[OFF_NORMAL + (size_t)ray * 3 + 2] = swn2 * inv_ws;
    }
}

extern "C" void kernel_launch(void* const* d_in, const int* in_sizes, int n_in,
                              void* d_out, int out_size, void* d_ws, size_t ws_size,
                              hipStream_t stream) {
    const float* colors       = (const float*)d_in[0];
    const float* sdfs         = (const float*)d_in[1];
    const float* depths       = (const float*)d_in[2];
    const float* normals      = (const float*)d_in[3];
    const float* ray_dirs     = (const float*)d_in[4];
    const float* real_normals = (const float*)d_in[5];
    const float* inv_std_p    = (const float*)d_in[6];
    float* out = (float*)d_out;

    dim3 grid(NRAYS / 4);   // 4 waves (rays) per 256-thread block
    dim3 block(256);
    hipLaunchKernelGGL(march_kernel, grid, block, 0, stream,
                       colors, sdfs, depths, normals, ray_dirs, real_normals,
                       inv_std_p, out);
}

// Round 2
// 166.623 us; speedup vs baseline: 1.0165x; 1.0165x over previous
//
#include <hip/hip_runtime.h>

// MipRayMarcher2: NeuS-style alpha compositing.
// 4 rays per wave: 16 lanes/ray, 3 samples per lane (S=48, intervals SM=47).
// All shuffles (width 16) serve 4 rays per instruction.

static constexpr int NRAYS = 65536;          // B*R = 4*16384
static constexpr int S_ = 48;
static constexpr int SM = 47;
static constexpr int OFF_DEPTH  = NRAYS * 3;             // 196608
static constexpr int OFF_W      = OFF_DEPTH + NRAYS;     // 262144
static constexpr int OFF_NORMAL = OFF_W + NRAYS * SM;    // 3342336

struct F3 { float x, y, z; };

__global__ __launch_bounds__(256) void march_kernel(
    const float* __restrict__ colors,
    const float* __restrict__ sdfs,
    const float* __restrict__ depths,
    const float* __restrict__ normals,
    const float* __restrict__ ray_dirs,
    const float* __restrict__ real_normals,
    const float* __restrict__ inv_std_p,
    float* __restrict__ out)
{
    const int tid = blockIdx.x * 256 + threadIdx.x;
    const int ray = tid >> 4;                 // 16 lanes per ray
    const int sl  = threadIdx.x & 15;         // sub-lane within ray group

    // Wave-uniform constants. Fold log2(e) and the 0.5 mid-point scaling:
    //   est_prev*inv_std*log2e = ss*uu - mq ; est_next*... = ss*uu + mq
    // where ss = sd_i + sd_{i+1} (unscaled sum), mq = min(dots,0)*delta*qq,
    // dots = dot(dir, n_i + n_{i+1}) (unscaled).
    const float L2E = 1.4426950408889634f;
    const float inv_std = fminf(fmaxf(__expf(inv_std_p[0] * 10.0f), 1e-6f), 1e6f);
    const float uu = inv_std * (0.5f  * L2E);
    const float qq = inv_std * (0.25f * L2E);

    const F3 dir = ((const F3*)ray_dirs)[ray];

    const int sbase = ray * 16 + sl;          // F3 index into sdfs/depths
    const int cbase = ray * 48 + sl * 3;      // F3 index into colors/normals/real_normals

    // Load this lane's 3 samples.
    const F3 sd3 = ((const F3*)sdfs)[sbase];
    const F3 dp3 = ((const F3*)depths)[sbase];
    F3 c[3], n[3], r[3];
#pragma unroll
    for (int j = 0; j < 3; ++j) {
        c[j] = ((const F3*)colors)[cbase + j];
        n[j] = ((const F3*)normals)[cbase + j];
        r[j] = ((const F3*)real_normals)[cbase + j];
    }

    // Neighbor lane's first sample (sample 3*(sl+1)) via width-16 shuffles.
    // For sl==15 the result is garbage; that interval (47) is masked out.
    const float sdN = __shfl_down(sd3.x, 1, 16);
    const float dpN = __shfl_down(dp3.x, 1, 16);
    const float c0N = __shfl_down(c[0].x, 1, 16);
    const float c1N = __shfl_down(c[0].y, 1, 16);
    const float c2N = __shfl_down(c[0].z, 1, 16);
    const float n0N = __shfl_down(n[0].x, 1, 16);
    const float n1N = __shfl_down(n[0].y, 1, 16);
    const float n2N = __shfl_down(n[0].z, 1, 16);
    const float r0N = __shfl_down(r[0].x, 1, 16);
    const float r1N = __shfl_down(r[0].y, 1, 16);
    const float r2N = __shfl_down(r[0].z, 1, 16);

    // 4-sample component arrays (sample 3 = neighbor's sample 0).
    const float SD[4] = { sd3.x, sd3.y, sd3.z, sdN };
    const float DP[4] = { dp3.x, dp3.y, dp3.z, dpN };
    const float C0[4] = { c[0].x, c[1].x, c[2].x, c0N };
    const float C1[4] = { c[0].y, c[1].y, c[2].y, c1N };
    const float C2[4] = { c[0].z, c[1].z, c[2].z, c2N };
    const float N0[4] = { n[0].x, n[1].x, n[2].x, n0N };
    const float N1[4] = { n[0].y, n[1].y, n[2].y, n1N };
    const float N2[4] = { n[0].z, n[1].z, n[2].z, n2N };
    const float R0[4] = { r[0].x, r[1].x, r[2].x, r0N };
    const float R1[4] = { r[0].y, r[1].y, r[2].y, r1N };
    const float R2[4] = { r[0].z, r[1].z, r[2].z, r2N };

    float al[3], tt[3];
    float cs0[3], cs1[3], cs2[3], dsum[3], rs0[3], rs1[3], rs2[3];

#pragma unroll
    for (int j = 0; j < 3; ++j) {
        const float delta = DP[j + 1] - DP[j];
        cs0[j]  = C0[j] + C0[j + 1];
        cs1[j]  = C1[j] + C1[j + 1];
        cs2[j]  = C2[j] + C2[j + 1];
        dsum[j] = DP[j] + DP[j + 1];
        rs0[j]  = R0[j] + R0[j + 1];
        rs1[j]  = R1[j] + R1[j + 1];
        rs2[j]  = R2[j] + R2[j + 1];
        const float ss  = SD[j] + SD[j + 1];
        const float ns0 = N0[j] + N0[j + 1];
        const float ns1 = N1[j] + N1[j + 1];
        const float ns2 = N2[j] + N2[j + 1];

        const float dots = dir.x * ns0 + dir.y * ns1 + dir.z * ns2;
        const float mn   = fminf(dots, 0.0f);
        const float mq   = mn * delta * qq;
        const float base = ss * uu;
        // prev_cdf = sigmoid(est_prev*inv_std) = 1/(1+exp2(mq - base))
        const float ep = __builtin_amdgcn_exp2f(mq - base);
        const float pc = __builtin_amdgcn_rcpf(1.0f + ep);
        // next_cdf = 1/(1+exp2(-(mq + base)))
        const float en = __builtin_amdgcn_exp2f(-(mq + base));
        const float nc = __builtin_amdgcn_rcpf(1.0f + en);

        float a = (pc - nc + 1e-5f) * __builtin_amdgcn_rcpf(pc + 1e-5f);
        a = fminf(fmaxf(a, 0.0f), 1.0f);
        const bool valid = (j < 2) | (sl < 15);   // interval 47 does not exist
        if (!valid) a = 0.0f;
        al[j] = a;
        tt[j] = 1.0f - a + 1e-10f;
    }

    // Inclusive scan (width 16) of the per-lane product of t's.
    float p = tt[0] * tt[1] * tt[2];
#pragma unroll
    for (int off = 1; off < 16; off <<= 1) {
        const float v = __shfl_up(p, off, 16);
        if (sl >= off) p *= v;
    }
    float excl = __shfl_up(p, 1, 16);
    if (sl == 0) excl = 1.0f;

    const float T0 = excl;
    const float T1 = excl * tt[0];
    const float T2 = T1 * tt[1];
    const float w0 = al[0] * T0;
    const float w1 = al[1] * T1;
    const float w2 = al[2] * T2;

    // Per-lane partial sums (note: cs/dsum/rs are 2x the mids).
    float ws  = w0 + w1 + w2;
    float sc0 = w0 * cs0[0] + w1 * cs0[1] + w2 * cs0[2];
    float sc1 = w0 * cs1[0] + w1 * cs1[1] + w2 * cs1[2];
    float sc2 = w0 * cs2[0] + w1 * cs2[1] + w2 * cs2[2];
    float sdp = w0 * dsum[0] + w1 * dsum[1] + w2 * dsum[2];
    float sr0 = w0 * rs0[0] + w1 * rs0[1] + w2 * rs0[2];
    float sr1 = w0 * rs1[0] + w1 * rs1[1] + w2 * rs1[2];
    float sr2 = w0 * rs2[0] + w1 * rs2[1] + w2 * rs2[2];

    // Butterfly reduction within each 16-lane ray group.
#pragma unroll
    for (int m = 8; m > 0; m >>= 1) {
        ws  += __shfl_xor(ws,  m, 16);
        sc0 += __shfl_xor(sc0, m, 16);
        sc1 += __shfl_xor(sc1, m, 16);
        sc2 += __shfl_xor(sc2, m, 16);
        sdp += __shfl_xor(sdp, m, 16);
        sr0 += __shfl_xor(sr0, m, 16);
        sr1 += __shfl_xor(sr1, m, 16);
        sr2 += __shfl_xor(sr2, m, 16);
    }

    // Weights output (intervals 3*sl .. 3*sl+2).
    const int wbase = OFF_W + ray * SM + sl * 3;
    out[wbase + 0] = w0;
    out[wbase + 1] = w1;
    if (sl < 15) out[wbase + 2] = w2;

    if (sl == 0) {
        // cs sums are 2x mids -> scale rgb by 0.5; the 2x cancels in the
        // weight-normalized depth/normal, handled via 0.5*inv_ws.
        out[ray * 3 + 0] = 0.5f * sc0;
        out[ray * 3 + 1] = 0.5f * sc1;
        out[ray * 3 + 2] = 0.5f * sc2;
        const float hiw = 0.5f * __builtin_amdgcn_rcpf(ws);  // ws >= ~5e-6 always
        out[OFF_DEPTH + ray] = sdp * hiw;
        out[OFF_NORMAL + ray * 3 + 0] = sr0 * hiw;
        out[OFF_NORMAL + ray * 3 + 1] = sr1 * hiw;
        out[OFF_NORMAL + ray * 3 + 2] = sr2 * hiw;
    }
}

extern "C" void kernel_launch(void* const* d_in, const int* in_sizes, int n_in,
                              void* d_out, int out_size, void* d_ws, size_t ws_size,
                              hipStream_t stream) {
    const float* colors       = (const float*)d_in[0];
    const float* sdfs         = (const float*)d_in[1];
    const float* depths       = (const float*)d_in[2];
    const float* normals      = (const float*)d_in[3];
    const float* ray_dirs     = (const float*)d_in[4];
    const float* real_normals = (const float*)d_in[5];
    const float* inv_std_p    = (const float*)d_in[6];
    float* out = (float*)d_out;

    // 16 threads per ray, 65536 rays -> 1M threads -> 4096 blocks of 256.
    dim3 grid(NRAYS * 16 / 256);
    dim3 block(256);
    hipLaunchKernelGGL(march_kernel, grid, block, 0, stream,
                       colors, sdfs, depths, normals, ray_dirs, real_normals,
                       inv_std_p, out);
}

// Round 3
// 164.819 us; speedup vs baseline: 1.0276x; 1.0109x over previous
//
#include <hip/hip_runtime.h>

// MipRayMarcher2: NeuS-style alpha compositing.
// 4 rays per wave: 16 lanes/ray, 3 samples per lane (S=48, intervals SM=47).
// ALL cross-lane traffic via DPP row ops (16-lane rows == our ray groups):
// no ds_bpermute, no LDS pipe, no lgkmcnt on the critical path.

static constexpr int NRAYS = 65536;          // B*R = 4*16384
static constexpr int SM = 47;
static constexpr int OFF_DEPTH  = NRAYS * 3;             // 196608
static constexpr int OFF_W      = OFF_DEPTH + NRAYS;     // 262144
static constexpr int OFF_NORMAL = OFF_W + NRAYS * SM;    // 3342336

struct F3 { float x, y, z; };

// DPP move: dst[i] = src[mapped lane in 16-lane row]; invalid lanes keep `old`.
template <int CTRL>
__device__ __forceinline__ float dpp_mov(float x, float old) {
    return __builtin_bit_cast(float,
        __builtin_amdgcn_update_dpp(__builtin_bit_cast(int, old),
                                    __builtin_bit_cast(int, x),
                                    CTRL, 0xF, 0xF, false));
}
// ctrl encodings: row_shl:N = 0x100+N (lane i <- i+... data to higher lanes? see use),
//                 row_shr:N = 0x110+N (lane i <- lane i-N),
//                 row_ror:N = 0x120+N (rotate within 16-lane row).
#define ROW_SHL1 0x101     // lane i <- lane i+1  (shfl_down 1 within row)
#define ROW_SHR(n) (0x110 + (n))
#define ROW_ROR(n) (0x120 + (n))

__device__ __forceinline__ float row_nbr(float x) {       // value from lane i+1
    return dpp_mov<ROW_SHL1>(x, x);                       // lane15: keep own (masked later)
}

// Sum across the 16-lane row via rotation tree; all lanes end with the total.
__device__ __forceinline__ float row_sum16(float x) {
    x += dpp_mov<ROW_ROR(8)>(x, 0.0f);
    x += dpp_mov<ROW_ROR(4)>(x, 0.0f);
    x += dpp_mov<ROW_ROR(2)>(x, 0.0f);
    x += dpp_mov<ROW_ROR(1)>(x, 0.0f);
    return x;
}

__global__ __launch_bounds__(256) void march_kernel(
    const float* __restrict__ colors,
    const float* __restrict__ sdfs,
    const float* __restrict__ depths,
    const float* __restrict__ normals,
    const float* __restrict__ ray_dirs,
    const float* __restrict__ real_normals,
    const float* __restrict__ inv_std_p,
    float* __restrict__ out)
{
    const int tid = blockIdx.x * 256 + threadIdx.x;
    const int ray = tid >> 4;                 // 16 lanes per ray
    const int sl  = threadIdx.x & 15;         // sub-lane within ray group (DPP row)

    // Wave-uniform constants; fold log2(e) and the 0.5 midpoint scaling.
    const float L2E = 1.4426950408889634f;
    const float inv_std = fminf(fmaxf(__expf(inv_std_p[0] * 10.0f), 1e-6f), 1e6f);
    const float uu = inv_std * (0.5f  * L2E);
    const float qq = inv_std * (0.25f * L2E);

    const F3 dir = ((const F3*)ray_dirs)[ray];

    const int sbase = ray * 16 + sl;          // F3 index into sdfs/depths
    const int cbase = ray * 48 + sl * 3;      // F3 index into colors/normals/real_normals

    const F3 sd3 = ((const F3*)sdfs)[sbase];
    const F3 dp3 = ((const F3*)depths)[sbase];
    F3 c[3], n[3], r[3];
#pragma unroll
    for (int j = 0; j < 3; ++j) {
        c[j] = ((const F3*)colors)[cbase + j];
        n[j] = ((const F3*)normals)[cbase + j];
        r[j] = ((const F3*)real_normals)[cbase + j];
    }

    // Neighbor lane's first sample (= this ray-group's sample 3*(sl+1)) via DPP.
    const float sdN = row_nbr(sd3.x);
    const float dpN = row_nbr(dp3.x);
    const float c0N = row_nbr(c[0].x);
    const float c1N = row_nbr(c[0].y);
    const float c2N = row_nbr(c[0].z);
    const float n0N = row_nbr(n[0].x);
    const float n1N = row_nbr(n[0].y);
    const float n2N = row_nbr(n[0].z);
    const float r0N = row_nbr(r[0].x);
    const float r1N = row_nbr(r[0].y);
    const float r2N = row_nbr(r[0].z);

    const float SD[4] = { sd3.x, sd3.y, sd3.z, sdN };
    const float DP[4] = { dp3.x, dp3.y, dp3.z, dpN };
    const float C0[4] = { c[0].x, c[1].x, c[2].x, c0N };
    const float C1[4] = { c[0].y, c[1].y, c[2].y, c1N };
    const float C2[4] = { c[0].z, c[1].z, c[2].z, c2N };
    const float N0[4] = { n[0].x, n[1].x, n[2].x, n0N };
    const float N1[4] = { n[0].y, n[1].y, n[2].y, n1N };
    const float N2[4] = { n[0].z, n[1].z, n[2].z, n2N };
    const float R0[4] = { r[0].x, r[1].x, r[2].x, r0N };
    const float R1[4] = { r[0].y, r[1].y, r[2].y, r1N };
    const float R2[4] = { r[0].z, r[1].z, r[2].z, r2N };

    float al[3], tt[3];
    float cs0[3], cs1[3], cs2[3], dsum[3], rs0[3], rs1[3], rs2[3];

#pragma unroll
    for (int j = 0; j < 3; ++j) {
        const float delta = DP[j + 1] - DP[j];
        cs0[j]  = C0[j] + C0[j + 1];
        cs1[j]  = C1[j] + C1[j + 1];
        cs2[j]  = C2[j] + C2[j + 1];
        dsum[j] = DP[j] + DP[j + 1];
        rs0[j]  = R0[j] + R0[j + 1];
        rs1[j]  = R1[j] + R1[j + 1];
        rs2[j]  = R2[j] + R2[j + 1];
        const float ss  = SD[j] + SD[j + 1];
        const float ns0 = N0[j] + N0[j + 1];
        const float ns1 = N1[j] + N1[j + 1];
        const float ns2 = N2[j] + N2[j + 1];

        const float dots = dir.x * ns0 + dir.y * ns1 + dir.z * ns2;
        const float mn   = fminf(dots, 0.0f);
        const float mq   = mn * delta * qq;
        const float base = ss * uu;
        // prev_cdf = 1/(1+exp2(mq-base)); next_cdf = 1/(1+exp2(-(mq+base)))
        const float ep = __builtin_amdgcn_exp2f(mq - base);
        const float pc = __builtin_amdgcn_rcpf(1.0f + ep);
        const float en = __builtin_amdgcn_exp2f(-(mq + base));
        const float nc = __builtin_amdgcn_rcpf(1.0f + en);

        float a = (pc - nc + 1e-5f) * __builtin_amdgcn_rcpf(pc + 1e-5f);
        a = fminf(fmaxf(a, 0.0f), 1.0f);
        const bool valid = (j < 2) | (sl < 15);   // interval 47 does not exist
        if (!valid) a = 0.0f;
        al[j] = a;
        tt[j] = 1.0f - a + 1e-10f;
    }

    // Inclusive multiply-scan over the row of per-lane products (DPP, identity=1).
    float p = tt[0] * tt[1] * tt[2];
    p *= dpp_mov<ROW_SHR(1)>(p, 1.0f);
    p *= dpp_mov<ROW_SHR(2)>(p, 1.0f);
    p *= dpp_mov<ROW_SHR(4)>(p, 1.0f);
    p *= dpp_mov<ROW_SHR(8)>(p, 1.0f);
    const float excl = dpp_mov<ROW_SHR(1)>(p, 1.0f);   // lane 0 -> 1.0

    const float T0 = excl;
    const float T1 = excl * tt[0];
    const float T2 = T1 * tt[1];
    const float w0 = al[0] * T0;
    const float w1 = al[1] * T1;
    const float w2 = al[2] * T2;

    // Per-lane partials (cs/dsum/rs are 2x the mids; fixed in epilogue).
    float ws  = w0 + w1 + w2;
    float sc0 = w0 * cs0[0] + w1 * cs0[1] + w2 * cs0[2];
    float sc1 = w0 * cs1[0] + w1 * cs1[1] + w2 * cs1[2];
    float sc2 = w0 * cs2[0] + w1 * cs2[1] + w2 * cs2[2];
    float sdp = w0 * dsum[0] + w1 * dsum[1] + w2 * dsum[2];
    float sr0 = w0 * rs0[0] + w1 * rs0[1] + w2 * rs0[2];
    float sr1 = w0 * rs1[0] + w1 * rs1[1] + w2 * rs1[2];
    float sr2 = w0 * rs2[0] + w1 * rs2[1] + w2 * rs2[2];

    ws  = row_sum16(ws);
    sc0 = row_sum16(sc0);
    sc1 = row_sum16(sc1);
    sc2 = row_sum16(sc2);
    sdp = row_sum16(sdp);
    sr0 = row_sum16(sr0);
    sr1 = row_sum16(sr1);
    sr2 = row_sum16(sr2);

    // Weights output (intervals 3*sl .. 3*sl+2).
    const int wbase = OFF_W + ray * SM + sl * 3;
    out[wbase + 0] = w0;
    out[wbase + 1] = w1;
    if (sl < 15) out[wbase + 2] = w2;

    if (sl == 0) {
        out[ray * 3 + 0] = 0.5f * sc0;
        out[ray * 3 + 1] = 0.5f * sc1;
        out[ray * 3 + 2] = 0.5f * sc2;
        const float hiw = 0.5f * __builtin_amdgcn_rcpf(ws);  // ws >= ~5e-6 always
        out[OFF_DEPTH + ray] = sdp * hiw;
        out[OFF_NORMAL + ray * 3 + 0] = sr0 * hiw;
        out[OFF_NORMAL + ray * 3 + 1] = sr1 * hiw;
        out[OFF_NORMAL + ray * 3 + 2] = sr2 * hiw;
    }
}

extern "C" void kernel_launch(void* const* d_in, const int* in_sizes, int n_in,
                              void* d_out, int out_size, void* d_ws, size_t ws_size,
                              hipStream_t stream) {
    const float* colors       = (const float*)d_in[0];
    const float* sdfs         = (const float*)d_in[1];
    const float* depths       = (const float*)d_in[2];
    const float* normals      = (const float*)d_in[3];
    const float* ray_dirs     = (const float*)d_in[4];
    const float* real_normals = (const float*)d_in[5];
    const float* inv_std_p    = (const float*)d_in[6];
    float* out = (float*)d_out;

    dim3 grid(NRAYS * 16 / 256);   // 4096 blocks
    dim3 block(256);
    hipLaunchKernelGGL(march_kernel, grid, block, 0, stream,
                       colors, sdfs, depths, normals, ray_dirs, real_normals,
                       inv_std_p, out);
}